// Round 2
// baseline (165.891 us; speedup 1.0000x reference)
//
#include <hip/hip_runtime.h>
#include <math.h>

#define N_HITS 100000
#define P_PART 300
#define Q_MIN 0.01f
#define R_THLD 10.0f
#define PT_THLD 0.9f

// ws layout (bytes):
//   [0,    2400): unsigned long long best[300]   (zeroed)
//   [2432, 2448): double sums[2]  {att_num, rep_sum}  (zeroed)
//   [2448, 2452): int nmask                      (zeroed)
//   [2464, 3664): float q_a[300]
//   [3664, 8464): float4 x_a[300]

__global__ void k1_scan(const float* __restrict__ beta,
                        const int* __restrict__ pid,
                        const int* __restrict__ recon,
                        const float* __restrict__ tp,
                        unsigned long long* __restrict__ best,
                        int* __restrict__ nmask) {
    int i = blockIdx.x * blockDim.x + threadIdx.x;
    if (i >= N_HITS) return;
    float a = atanhf(beta[i]);
    float q = a * a + Q_MIN;
    int p = pid[i];
    if (p > 0) {
        // q > 0 always, so float bit pattern orders identically to value.
        // Low word ~i => on exact ties the SMALLEST index wins (jnp.argmax semantics).
        unsigned long long pack =
            ((unsigned long long)__float_as_uint(q) << 32) |
            (unsigned long long)(~(unsigned int)i);
        atomicMax(&best[p - 1], pack);
    }
    if (recon[i] > 0 && tp[i] > PT_THLD) atomicAdd(nmask, 1);
}

__global__ void k2_centers(const float* __restrict__ beta,
                           const float* __restrict__ x,
                           const unsigned long long* __restrict__ best,
                           float* __restrict__ q_a,
                           float4* __restrict__ x_a) {
    int p = blockIdx.x * blockDim.x + threadIdx.x;
    if (p >= P_PART) return;
    unsigned long long b = best[p];
    unsigned int idx = (b == 0ULL) ? 0u : ~(unsigned int)(b & 0xffffffffULL);
    float a = atanhf(beta[idx]);
    q_a[p] = a * a + Q_MIN;
    x_a[p] = reinterpret_cast<const float4*>(x)[idx];
}

__global__ __launch_bounds__(256) void k3_main(
        const float* __restrict__ beta,
        const float* __restrict__ x,
        const int* __restrict__ pid,
        const int* __restrict__ recon,
        const float* __restrict__ tp,
        const float* __restrict__ q_a,
        const float4* __restrict__ x_a,
        double* __restrict__ sums) {
    __shared__ float4 xa_s[P_PART];
    __shared__ float  qa_s[P_PART];
    for (int p = threadIdx.x; p < P_PART; p += blockDim.x) {
        xa_s[p] = x_a[p];
        qa_s[p] = q_a[p];
    }
    __syncthreads();

    int i = blockIdx.x * blockDim.x + threadIdx.x;
    float att = 0.f, rep = 0.f;
    if (i < N_HITS) {
        float a = atanhf(beta[i]);
        float q = a * a + Q_MIN;
        int pm1 = pid[i] - 1;                 // -1 for noise (matches no p)
        bool m = (recon[i] > 0) && (tp[i] > PT_THLD);
        float4 xi = reinterpret_cast<const float4*>(x)[i];
        float att_acc = 0.f, rep_acc = 0.f;
        #pragma unroll 4
        for (int p = 0; p < P_PART; ++p) {
            float4 xa = xa_s[p];
            float qa = qa_s[p];
            float dx = xi.x - xa.x, dy = xi.y - xa.y;
            float dz = xi.z - xa.z, dw = xi.w - xa.w;
            float nsq = dx * dx + dy * dy + dz * dz + dw * dw;
            float t = R_THLD - sqrtf(nsq + 1e-8f);
            if (p == pm1) {
                att_acc += nsq * qa;          // attractive: own pid only
            } else {
                rep_acc += fmaxf(t, 0.f) * qa; // repulsive: all other pids
            }
        }
        att = m ? q * att_acc : 0.f;
        rep = q * rep_acc;
    }
    // wave-64 shuffle reduction
    #pragma unroll
    for (int off = 32; off > 0; off >>= 1) {
        att += __shfl_down(att, off, 64);
        rep += __shfl_down(rep, off, 64);
    }
    if ((threadIdx.x & 63) == 0) {
        atomicAdd(&sums[0], (double)att);
        atomicAdd(&sums[1], (double)rep);
    }
}

__global__ void k4_fin(const double* __restrict__ sums,
                       const int* __restrict__ nmask,
                       float* __restrict__ out) {
    if (threadIdx.x == 0) {
        out[0] = (float)(sums[0] / (double)(*nmask));
        out[1] = (float)(sums[1] / (double)N_HITS);
    }
}

extern "C" void kernel_launch(void* const* d_in, const int* in_sizes, int n_in,
                              void* d_out, int out_size, void* d_ws, size_t ws_size,
                              hipStream_t stream) {
    const float* beta  = (const float*)d_in[0];
    const float* x     = (const float*)d_in[1];
    const int*   pid   = (const int*)d_in[2];
    const int*   recon = (const int*)d_in[3];
    const float* tp    = (const float*)d_in[4];
    float* out = (float*)d_out;

    char* ws = (char*)d_ws;
    unsigned long long* best = (unsigned long long*)(ws);
    double* sums  = (double*)(ws + 2432);
    int*    nmask = (int*)(ws + 2448);
    float*  q_a   = (float*)(ws + 2464);
    float4* x_a   = (float4*)(ws + 3664);

    hipMemsetAsync(d_ws, 0, 2464, stream);  // zero best/sums/nmask (ws is 0xAA-poisoned)

    k1_scan<<<(N_HITS + 255) / 256, 256, 0, stream>>>(beta, pid, recon, tp, best, nmask);
    k2_centers<<<2, 256, 0, stream>>>(beta, x, best, q_a, x_a);
    k3_main<<<(N_HITS + 255) / 256, 256, 0, stream>>>(beta, x, pid, recon, tp, q_a, x_a, sums);
    k4_fin<<<1, 64, 0, stream>>>(sums, nmask, out);
}

// Round 3
// 138.845 us; speedup vs baseline: 1.1948x; 1.1948x over previous
//
#include <hip/hip_runtime.h>
#include <math.h>

#define N_HITS 100000
#define P_PART 300
#define NSPLIT 4
#define PB (P_PART / NSPLIT)   // 75
#define NBINS 16
#define Q_MIN 0.01f
#define R_THLD 10.0f
#define PT_THLD 0.9f

// ws layout (bytes):
//   [0,    2400): u64 best[300]                (zeroed)
//   [2400, 2404): u32 doneA                    (zeroed)
//   [2404, 2408): u32 doneB                    (zeroed)
//   [2408, 2412): u32 nmask                    (zeroed)
//   [2416, 2672): double bins[16][2]           (zeroed)
//   [2688, 12288): float4 c[600]  (c[2p]=x_a[p], c[2p+1].x=q_a[p]) 32B-aligned

__global__ __launch_bounds__(256) void kA_scan(
        const float* __restrict__ beta,
        const float* __restrict__ x,
        const int* __restrict__ pid,
        const int* __restrict__ recon,
        const float* __restrict__ tp,
        unsigned long long* __restrict__ best,
        unsigned int* __restrict__ nmask,
        unsigned int* __restrict__ doneA,
        float4* __restrict__ c,
        int nblocks) {
    int i = blockIdx.x * 256 + threadIdx.x;
    if (i < N_HITS) {
        float a = atanhf(beta[i]);
        float q = a * a + Q_MIN;
        int p = pid[i];
        if (p > 0) {
            // q > 0 -> float bits order like values. ~i => ties pick smallest i
            // (jnp.argmax first-occurrence semantics).
            unsigned long long pack =
                ((unsigned long long)__float_as_uint(q) << 32) |
                (unsigned long long)(~(unsigned int)i);
            atomicMax(&best[p - 1], pack);
        }
        if (recon[i] > 0 && tp[i] > PT_THLD) atomicAdd(nmask, 1u);
    }
    // last-finishing block gathers the condensation centers
    __shared__ int isLast;
    if (threadIdx.x == 0) {
        __threadfence();
        unsigned int old = atomicAdd(doneA, 1u);
        isLast = (old == (unsigned int)(nblocks - 1)) ? 1 : 0;
    }
    __syncthreads();
    if (isLast) {
        for (int p = threadIdx.x; p < P_PART; p += 256) {
            // atomic read -> guaranteed L2 (other blocks' atomicMax results)
            unsigned long long b = atomicOr(&best[p], 0ULL);
            unsigned int idx = (b == 0ULL) ? 0u : ~(unsigned int)(b & 0xffffffffULL);
            float a = atanhf(beta[idx]);
            c[2 * p] = reinterpret_cast<const float4*>(x)[idx];
            c[2 * p + 1] = make_float4(a * a + Q_MIN, 0.f, 0.f, 0.f);
        }
    }
}

__global__ __launch_bounds__(256) void kB_main(
        const float* __restrict__ beta,
        const float* __restrict__ x,
        const int* __restrict__ pid,
        const int* __restrict__ recon,
        const float* __restrict__ tp,
        const float4* __restrict__ c,
        const unsigned int* __restrict__ nmask,
        double* __restrict__ bins,
        unsigned int* __restrict__ doneB,
        float* __restrict__ out,
        int totalB) {
    int i = blockIdx.x * 256 + threadIdx.x;
    int p0 = blockIdx.y * PB;

    float att = 0.f, rep = 0.f;
    if (i < N_HITS) {
        float a = atanhf(beta[i]);
        float q = a * a + Q_MIN;
        float4 xi = reinterpret_cast<const float4*>(x)[i];
        float racc = 0.f;
        #pragma unroll 5
        for (int p = p0; p < p0 + PB; ++p) {
            float4 xa = c[2 * p];          // uniform index -> scalar load
            float qa = c[2 * p + 1].x;
            float dx = xi.x - xa.x, dy = xi.y - xa.y;
            float dz = xi.z - xa.z, dw = xi.w - xa.w;
            float nsq = dx * dx + dy * dy + dz * dz + dw * dw;
            racc += fmaxf(R_THLD - sqrtf(nsq + 1e-8f), 0.f) * qa;
        }
        rep = q * racc;
        int pm1 = pid[i] - 1;
        if (pm1 >= p0 && pm1 < p0 + PB) {   // this split owns the own-pid term
            float4 xa = c[2 * pm1];         // per-lane gather (L2-resident)
            float qa = c[2 * pm1 + 1].x;
            float dx = xi.x - xa.x, dy = xi.y - xa.y;
            float dz = xi.z - xa.z, dw = xi.w - xa.w;
            float nsq = dx * dx + dy * dy + dz * dz + dw * dw;
            rep -= q * fmaxf(R_THLD - sqrtf(nsq + 1e-8f), 0.f) * qa;
            if (recon[i] > 0 && tp[i] > PT_THLD) att = q * nsq * qa;
        }
    }

    // wave reduce
    #pragma unroll
    for (int off = 32; off > 0; off >>= 1) {
        att += __shfl_down(att, off, 64);
        rep += __shfl_down(rep, off, 64);
    }
    __shared__ float sA[4], sR[4];
    __shared__ int isLast;
    int wid = threadIdx.x >> 6;
    if ((threadIdx.x & 63) == 0) { sA[wid] = att; sR[wid] = rep; }
    __syncthreads();
    if (threadIdx.x == 0) {
        float A = sA[0] + sA[1] + sA[2] + sA[3];
        float R = sR[0] + sR[1] + sR[2] + sR[3];
        int bin = (int)((blockIdx.y * gridDim.x + blockIdx.x) & (NBINS - 1));
        atomicAdd(&bins[2 * bin], (double)A);
        atomicAdd(&bins[2 * bin + 1], (double)R);
        __threadfence();
        unsigned int old = atomicAdd(doneB, 1u);
        isLast = (old == (unsigned int)(totalB - 1)) ? 1 : 0;
    }
    __syncthreads();
    if (isLast && threadIdx.x < 64) {
        double a = 0.0, r = 0.0;
        if (threadIdx.x < NBINS) {
            a = atomicAdd(&bins[2 * threadIdx.x], 0.0);      // L2 read
            r = atomicAdd(&bins[2 * threadIdx.x + 1], 0.0);
        }
        #pragma unroll
        for (int off = 8; off > 0; off >>= 1) {
            a += __shfl_down(a, off, 64);
            r += __shfl_down(r, off, 64);
        }
        if (threadIdx.x == 0) {
            out[0] = (float)(a / (double)(*nmask));
            out[1] = (float)(r / (double)N_HITS);
        }
    }
}

extern "C" void kernel_launch(void* const* d_in, const int* in_sizes, int n_in,
                              void* d_out, int out_size, void* d_ws, size_t ws_size,
                              hipStream_t stream) {
    const float* beta  = (const float*)d_in[0];
    const float* x     = (const float*)d_in[1];
    const int*   pid   = (const int*)d_in[2];
    const int*   recon = (const int*)d_in[3];
    const float* tp    = (const float*)d_in[4];
    float* out = (float*)d_out;

    char* ws = (char*)d_ws;
    unsigned long long* best  = (unsigned long long*)(ws);
    unsigned int*       doneA = (unsigned int*)(ws + 2400);
    unsigned int*       doneB = (unsigned int*)(ws + 2404);
    unsigned int*       nmask = (unsigned int*)(ws + 2408);
    double*             bins  = (double*)(ws + 2416);
    float4*             c     = (float4*)(ws + 2688);

    const int nblocksA = (N_HITS + 255) / 256;        // 391
    const int totalB = nblocksA * NSPLIT;             // 1564

    hipMemsetAsync(d_ws, 0, 2672, stream);

    kA_scan<<<nblocksA, 256, 0, stream>>>(beta, x, pid, recon, tp,
                                          best, nmask, doneA, c, nblocksA);
    kB_main<<<dim3(nblocksA, NSPLIT), 256, 0, stream>>>(beta, x, pid, recon, tp,
                                                        c, nmask, bins, doneB,
                                                        out, totalB);
}

// Round 4
// 128.476 us; speedup vs baseline: 1.2912x; 1.0807x over previous
//
#include <hip/hip_runtime.h>
#include <math.h>

#define N_HITS 100000
#define P_PART 300
#define NSPLIT 12
#define PB (P_PART / NSPLIT)   // 25 centers per y-split
#define HPT 4                  // hits per thread
#define TILE (256 * HPT)       // 1024 hits per block-x
#define NBINS 16
#define Q_MIN 0.01f
#define R_THLD 10.0f
#define PT_THLD 0.9f

// ws layout (bytes):
//   [0,    2400): u64 best[300]                (zeroed)
//   [2400, 2404): u32 doneA                    (zeroed)
//   [2404, 2408): u32 doneB                    (zeroed)
//   [2408, 2412): u32 nmask                    (zeroed)
//   [2416, 2672): double bins[16][2]           (zeroed)
//   [2688, 12288): float4 c[600]  (c[2p]=x_a[p], c[2p+1].x=q_a[p])

__global__ __launch_bounds__(256) void kA_scan(
        const float* __restrict__ beta,
        const float* __restrict__ x,
        const int* __restrict__ pid,
        const int* __restrict__ recon,
        const float* __restrict__ tp,
        unsigned long long* __restrict__ best,
        unsigned int* __restrict__ nmask,
        unsigned int* __restrict__ doneA,
        float4* __restrict__ c,
        int nblocks) {
    int i = blockIdx.x * 256 + threadIdx.x;
    if (i < N_HITS) {
        float a = atanhf(beta[i]);
        float q = a * a + Q_MIN;
        int p = pid[i];
        if (p > 0) {
            // q > 0 -> float bits order like values. ~i => ties pick smallest i
            // (jnp.argmax first-occurrence semantics).
            unsigned long long pack =
                ((unsigned long long)__float_as_uint(q) << 32) |
                (unsigned long long)(~(unsigned int)i);
            atomicMax(&best[p - 1], pack);
        }
        if (recon[i] > 0 && tp[i] > PT_THLD) atomicAdd(nmask, 1u);
    }
    // last-finishing block gathers the condensation centers
    __shared__ int isLast;
    if (threadIdx.x == 0) {
        __threadfence();
        unsigned int old = atomicAdd(doneA, 1u);
        isLast = (old == (unsigned int)(nblocks - 1)) ? 1 : 0;
    }
    __syncthreads();
    if (isLast) {
        for (int p = threadIdx.x; p < P_PART; p += 256) {
            unsigned long long b = atomicOr(&best[p], 0ULL);  // coherent read
            unsigned int idx = (b == 0ULL) ? 0u : ~(unsigned int)(b & 0xffffffffULL);
            float a = atanhf(beta[idx]);
            c[2 * p] = reinterpret_cast<const float4*>(x)[idx];
            c[2 * p + 1] = make_float4(a * a + Q_MIN, 0.f, 0.f, 0.f);
        }
    }
}

__global__ __launch_bounds__(256) void kB_main(
        const float* __restrict__ beta,
        const float* __restrict__ x,
        const int* __restrict__ pid,
        const int* __restrict__ recon,
        const float* __restrict__ tp,
        const float4* __restrict__ c,
        const unsigned int* __restrict__ nmask,
        double* __restrict__ bins,
        unsigned int* __restrict__ doneB,
        float* __restrict__ out,
        int totalB) {
    __shared__ float4 xa_s[PB];
    __shared__ float  qa_s[PB];
    int p0 = blockIdx.y * PB;
    if (threadIdx.x < PB) {
        xa_s[threadIdx.x] = c[2 * (p0 + threadIdx.x)];
        qa_s[threadIdx.x] = c[2 * (p0 + threadIdx.x) + 1].x;
    }
    __syncthreads();

    int base = blockIdx.x * TILE + threadIdx.x;
    float4 xi[HPT];
    float  q[HPT];
    float  racc[HPT];
    int    pm1[HPT];
    bool   m[HPT];
    #pragma unroll
    for (int h = 0; h < HPT; ++h) {
        int i = base + h * 256;
        bool valid = (i < N_HITS);
        int ii = valid ? i : 0;
        xi[h] = reinterpret_cast<const float4*>(x)[ii];
        float a = atanhf(beta[ii]);
        q[h] = valid ? (a * a + Q_MIN) : 0.f;   // q=0 nullifies OOB lanes
        pm1[h] = valid ? (pid[ii] - 1) : -1;
        m[h] = valid && (recon[ii] > 0) && (tp[ii] > PT_THLD);
        racc[h] = 0.f;
    }

    #pragma unroll 5
    for (int p = 0; p < PB; ++p) {
        float4 xa = xa_s[p];   // uniform -> LDS broadcast
        float  qa = qa_s[p];
        #pragma unroll
        for (int h = 0; h < HPT; ++h) {
            float dx = xi[h].x - xa.x, dy = xi[h].y - xa.y;
            float dz = xi[h].z - xa.z, dw = xi[h].w - xa.w;
            float nsq = dx * dx + dy * dy + dz * dz + dw * dw;
            racc[h] += fmaxf(R_THLD - sqrtf(nsq + 1e-8f), 0.f) * qa;
        }
    }

    float att = 0.f, rep = 0.f;
    #pragma unroll
    for (int h = 0; h < HPT; ++h) {
        rep += q[h] * racc[h];
        int lp = pm1[h] - p0;
        if (lp >= 0 && lp < PB) {           // this split owns the own-pid term
            float4 xa = xa_s[lp];           // LDS gather (rare path, once/hit)
            float  qa = qa_s[lp];
            float dx = xi[h].x - xa.x, dy = xi[h].y - xa.y;
            float dz = xi[h].z - xa.z, dw = xi[h].w - xa.w;
            float nsq = dx * dx + dy * dy + dz * dz + dw * dw;
            rep -= q[h] * fmaxf(R_THLD - sqrtf(nsq + 1e-8f), 0.f) * qa;
            if (m[h]) att += q[h] * nsq * qa;
        }
    }

    // wave-64 shuffle reduce, then block reduce
    #pragma unroll
    for (int off = 32; off > 0; off >>= 1) {
        att += __shfl_down(att, off, 64);
        rep += __shfl_down(rep, off, 64);
    }
    __shared__ float sA[4], sR[4];
    __shared__ int isLast;
    int wid = threadIdx.x >> 6;
    if ((threadIdx.x & 63) == 0) { sA[wid] = att; sR[wid] = rep; }
    __syncthreads();
    if (threadIdx.x == 0) {
        float A = sA[0] + sA[1] + sA[2] + sA[3];
        float R = sR[0] + sR[1] + sR[2] + sR[3];
        int bin = (int)((blockIdx.y * gridDim.x + blockIdx.x) & (NBINS - 1));
        atomicAdd(&bins[2 * bin], (double)A);
        atomicAdd(&bins[2 * bin + 1], (double)R);
        __threadfence();
        unsigned int old = atomicAdd(doneB, 1u);
        isLast = (old == (unsigned int)(totalB - 1)) ? 1 : 0;
    }
    __syncthreads();
    if (isLast && threadIdx.x < 64) {
        double a = 0.0, r = 0.0;
        if (threadIdx.x < NBINS) {
            a = atomicAdd(&bins[2 * threadIdx.x], 0.0);      // coherent read
            r = atomicAdd(&bins[2 * threadIdx.x + 1], 0.0);
        }
        #pragma unroll
        for (int off = 8; off > 0; off >>= 1) {
            a += __shfl_down(a, off, 64);
            r += __shfl_down(r, off, 64);
        }
        if (threadIdx.x == 0) {
            out[0] = (float)(a / (double)(*nmask));
            out[1] = (float)(r / (double)N_HITS);
        }
    }
}

extern "C" void kernel_launch(void* const* d_in, const int* in_sizes, int n_in,
                              void* d_out, int out_size, void* d_ws, size_t ws_size,
                              hipStream_t stream) {
    const float* beta  = (const float*)d_in[0];
    const float* x     = (const float*)d_in[1];
    const int*   pid   = (const int*)d_in[2];
    const int*   recon = (const int*)d_in[3];
    const float* tp    = (const float*)d_in[4];
    float* out = (float*)d_out;

    char* ws = (char*)d_ws;
    unsigned long long* best  = (unsigned long long*)(ws);
    unsigned int*       doneA = (unsigned int*)(ws + 2400);
    unsigned int*       doneB = (unsigned int*)(ws + 2404);
    unsigned int*       nmask = (unsigned int*)(ws + 2408);
    double*             bins  = (double*)(ws + 2416);
    float4*             c     = (float4*)(ws + 2688);

    const int nblocksA = (N_HITS + 255) / 256;          // 391
    const int nblocksBx = (N_HITS + TILE - 1) / TILE;   // 98
    const int totalB = nblocksBx * NSPLIT;              // 1176

    hipMemsetAsync(d_ws, 0, 2672, stream);

    kA_scan<<<nblocksA, 256, 0, stream>>>(beta, x, pid, recon, tp,
                                          best, nmask, doneA, c, nblocksA);
    kB_main<<<dim3(nblocksBx, NSPLIT), 256, 0, stream>>>(beta, x, pid, recon, tp,
                                                         c, nmask, bins, doneB,
                                                         out, totalB);
}